// Round 8
// baseline (606.972 us; speedup 1.0000x reference)
//
#include <hip/hip_runtime.h>
#include <hip/hip_bf16.h>
#include <math.h>

#define N_NODES 16384
#define T_TRI   65536
#define H_DIM   128
#define G_POOL  512
#define NITER   4
#define NLAY    4
#define RMAX    (T_TRI + 512)
#define MT      (RMAX / 128)      // 516 tiles of 128 rows

#define INV_STD 0.9999950000374996f

typedef __attribute__((ext_vector_type(8))) short bhalf8;
typedef __attribute__((ext_vector_type(4))) float f32x4;

__device__ __forceinline__ unsigned short f2b(float f) {
    unsigned int u = __float_as_uint(f);
    unsigned int r = (u + 0x7fffu + ((u >> 16) & 1u)) >> 16;
    return (unsigned short)r;
}

// ---------------- group classification / counting sort ----------------

__device__ __forceinline__ int group_of(int eij, int ejk, int nei) {
    return ((eij < nei) ? 0 : 2) + ((ejk < nei) ? 0 : 1);
}

__global__ void hist_k(const int* __restrict__ edxjk, const int* __restrict__ edxij,
                       const int* __restrict__ neip, int* __restrict__ ints) {
    __shared__ int lc[4];
    if (threadIdx.x < 4) lc[threadIdx.x] = 0;
    __syncthreads();
    int t = blockIdx.x * 256 + threadIdx.x;
    int nei = *neip;
    int g = group_of(edxij[t], edxjk[t], nei);
    atomicAdd(&lc[g], 1);
    __syncthreads();
    if (threadIdx.x < 4) atomicAdd(&ints[threadIdx.x], lc[threadIdx.x]);
}

__global__ void offsets_k(int* __restrict__ ints) {
    if (threadIdx.x == 0 && blockIdx.x == 0) {
        int a = 0;
        ints[8] = 0;  // aoff[0]
        for (int g = 0; g < 4; ++g) {
            a = (a + ints[g] + 127) & ~127;
            ints[9 + g] = a;  // aoff[g+1]
        }
    }
}

__global__ void scatter_k(const int* __restrict__ edxjk, const int* __restrict__ edxij,
                          const int* __restrict__ neip, int* __restrict__ ints,
                          int* __restrict__ rowmap) {
    int t = blockIdx.x * 256 + threadIdx.x;
    int nei = *neip;
    int g = group_of(edxij[t], edxjk[t], nei);
    int lane = threadIdx.x & 63;
    unsigned long long msame = 0;
    #pragma unroll
    for (int q = 0; q < 4; ++q) {
        unsigned long long mq = __ballot(g == q);
        if (g == q) msame = mq;
    }
    int leader = __ffsll((long long)msame) - 1;
    int rank = __popcll(msame & ((1ull << lane) - 1ull));
    int base = 0;
    if (lane == leader) base = atomicAdd(&ints[4 + g], __popcll(msame));
    base = __shfl(base, leader);
    int aoffg = ints[8 + g];
    rowmap[aoffg + base + rank] = t;
}

// ---------------- weight prep: LDS tile transpose, fp32 -> bf16 [n][k] ----------------

__global__ void t0_k(const float* __restrict__ W0, unsigned short* __restrict__ WT0) {
    __shared__ float t[32][33];
    int b = blockIdx.x;                 // 16 * 16 * 4 = 1024 tiles
    int ig = b >> 6;
    int kt = (b >> 2) & 15;
    int nt = b & 3;
    int tx = threadIdx.x & 31, ty = threadIdx.x >> 5;  // ty 0..7
    const float* src = W0 + ((size_t)ig * 512 + kt * 32) * 128 + nt * 32;
    #pragma unroll
    for (int q = 0; q < 4; ++q) { int r = q * 8 + ty; t[r][tx] = src[(size_t)r * 128 + tx]; }
    __syncthreads();
    unsigned short* dst = WT0 + ((size_t)ig * 128 + nt * 32) * 512 + kt * 32;
    #pragma unroll
    for (int q = 0; q < 4; ++q) { int r = q * 8 + ty; dst[(size_t)r * 512 + tx] = f2b(t[tx][r]); }
}

__global__ void th_k(const float* __restrict__ Wh, unsigned short* __restrict__ WTh) {
    __shared__ float t[32][33];
    int b = blockIdx.x;                 // 64 * 4 * 4 = 1024 tiles
    int ilg = b >> 4;
    int kt = (b >> 2) & 3;
    int nt = b & 3;
    int tx = threadIdx.x & 31, ty = threadIdx.x >> 5;
    const float* src = Wh + ((size_t)ilg * 128 + kt * 32) * 128 + nt * 32;
    #pragma unroll
    for (int q = 0; q < 4; ++q) { int r = q * 8 + ty; t[r][tx] = src[(size_t)r * 128 + tx]; }
    __syncthreads();
    unsigned short* dst = WTh + ((size_t)ilg * 128 + nt * 32) * 128 + kt * 32;
    #pragma unroll
    for (int q = 0; q < 4; ++q) { int r = q * 8 + ty; dst[(size_t)r * 128 + tx] = f2b(t[tx][r]); }
}

// ---------------- geo encoding ----------------

__global__ void geo_k(const float* __restrict__ pos, const int* __restrict__ eidx,
                      const float* __restrict__ Wg, const float* __restrict__ bg,
                      const float* __restrict__ gamg, const float* __restrict__ betg,
                      unsigned short* __restrict__ geob) {
    int t = blockIdx.x * 2 + (threadIdx.x >> 7);
    int h = threadIdx.x & 127;
    int ni = eidx[t], nj = eidx[T_TRI + t], nk = eidx[2 * T_TRI + t];
    float ix = pos[2 * ni], iy = pos[2 * ni + 1];
    float jx = pos[2 * nj], jy = pos[2 * nj + 1];
    float kx = pos[2 * nk], ky = pos[2 * nk + 1];
    float v1x = jx - ix, v1y = jy - iy;
    float v2x = kx - jx, v2y = ky - jy;
    float dij = sqrtf(v1x * v1x + v1y * v1y);
    float djk = sqrtf(v2x * v2x + v2y * v2y);
    float cr = v1x * v2y - v1y * v2x;
    float dt = v1x * v2x + v1y * v2y;
    float th = atan2f(fabsf(cr), dt);
    float v = dij * Wg[h] + djk * Wg[128 + h] + th * Wg[256 + h] + bg[h];
    v = v * (gamg[h] * INV_STD) + betg[h];
    v = fmaxf(v, 0.0f);
    geob[(size_t)t * 128 + h] = f2b(v);
}

// ---------------- fused per-interaction chain: GEMM0 + 4 hidden + scatter ----------------

__global__ __launch_bounds__(256, 2) void chain_k(
    const unsigned short* __restrict__ nfb, const unsigned short* __restrict__ geob,
    const int* __restrict__ eidx, const int* __restrict__ rowmap,
    const int* __restrict__ aoff, const unsigned short* __restrict__ WT0,
    const float* __restrict__ b0, const float* __restrict__ g0, const float* __restrict__ be0,
    const unsigned short* __restrict__ WTh,
    const float* __restrict__ bhp, const float* __restrict__ ghp, const float* __restrict__ behp,
    const float* __restrict__ att, float* __restrict__ nfout,
    int it, int skipnf) {
    __shared__ unsigned short sh[128 * 128];   // 32 KB h tile  [row][k] swizzled
    __shared__ unsigned short sw[128 * 128];   // 32 KB W tile  [n][k] swizzled; GEMM0: As+Bs
    unsigned short* As = sw;                   // [128*64]
    unsigned short* Bs = sw + 128 * 64;        // [128*64]

    const int r0 = blockIdx.x * 128;
    int g = 0;
    if (r0 >= aoff[1]) g = 1;
    if (r0 >= aoff[2]) g = 2;
    if (r0 >= aoff[3]) g = 3;
    const int tid = threadIdx.x;
    const int lane = tid & 63;
    const int wid = tid >> 6;
    const int wm = wid >> 1, wn = wid & 1;
    const int lr = lane & 15, lq = lane >> 4;

    f32x4 acc[4][4];
    const f32x4 zero4 = {0.f, 0.f, 0.f, 0.f};
    #pragma unroll
    for (int m = 0; m < 4; ++m)
        #pragma unroll
        for (int n = 0; n < 4; ++n) acc[m][n] = zero4;

    // ---- phase 0: GEMM0  [128 gathered rows, K=512] x [512,128] ----
    const unsigned short* Wt = WT0 + (size_t)(it * 4 + g) * 128 * 512;
    const int k0start = skipnf ? 384 : 0;   // it==0: nf==0, only geo region contributes
    for (int k0 = k0start; k0 < 512; k0 += 64) {
        const int region = k0 >> 7;   // 0:nf[i] 1:nf[j] 2:nf[k] 3:geo
        const int half = k0 & 127;
        #pragma unroll
        for (int p = 0; p < 4; ++p) {
            int e = p * 2048 + tid * 8;
            int row = e >> 6, col = e & 63;
            int tt = rowmap[r0 + row];
            int4 v = {0, 0, 0, 0};
            if (tt >= 0) {
                const unsigned short* src;
                if (region < 3) src = nfb + (size_t)eidx[region * T_TRI + tt] * 128 + half;
                else src = geob + (size_t)tt * 128 + half;
                v = *reinterpret_cast<const int4*>(src + col);
            }
            *reinterpret_cast<int4*>(&As[row * 64 + (((col >> 3) ^ (row & 7)) << 3)]) = v;
        }
        #pragma unroll
        for (int p = 0; p < 4; ++p) {
            int e = p * 2048 + tid * 8;
            int n = e >> 6, col = e & 63;
            int4 v = *reinterpret_cast<const int4*>(Wt + (size_t)n * 512 + k0 + col);
            *reinterpret_cast<int4*>(&Bs[n * 64 + (((col >> 3) ^ (n & 7)) << 3)]) = v;
        }
        __syncthreads();
        #pragma unroll
        for (int ks = 0; ks < 2; ++ks) {
            bhalf8 af[4], bf[4];
            #pragma unroll
            for (int m = 0; m < 4; ++m) {
                int row = 64 * wm + 16 * m + lr;
                int c8 = (4 * ks + lq) ^ (row & 7);
                af[m] = *reinterpret_cast<const bhalf8*>(&As[row * 64 + (c8 << 3)]);
            }
            #pragma unroll
            for (int n = 0; n < 4; ++n) {
                int nn = 64 * wn + 16 * n + lr;
                int c8 = (4 * ks + lq) ^ (nn & 7);
                bf[n] = *reinterpret_cast<const bhalf8*>(&Bs[nn * 64 + (c8 << 3)]);
            }
            #pragma unroll
            for (int m = 0; m < 4; ++m)
                #pragma unroll
                for (int n = 0; n < 4; ++n)
                    acc[m][n] = __builtin_amdgcn_mfma_f32_16x16x32_bf16(af[m], bf[n], acc[m][n], 0, 0, 0);
        }
        __syncthreads();   // final iter: all waves done with sw
    }

    int4 wreg[8];
    // preload W^0 (issues early; latency hides under epilogue VALU)
    {
        const unsigned short* Wl = WTh + (size_t)((it * NLAY + 0) * 4 + g) * 128 * 128;
        #pragma unroll
        for (int p = 0; p < 8; ++p) {
            int idx = p * 256 + tid;
            int n = idx >> 4, gd = idx & 15;
            wreg[p] = *reinterpret_cast<const int4*>(Wl + n * 128 + ((gd ^ (n & 7)) << 3));
        }
    }
    // h0 = relu(bn(acc)) -> sh (swizzled granules)
    {
        const float* bb = b0 + (it * 4 + g) * 128;
        const float* gg = g0 + (it * 4 + g) * 128;
        const float* be = be0 + (it * 4 + g) * 128;
        #pragma unroll
        for (int n = 0; n < 4; ++n) {
            int col = 64 * wn + 16 * n + lr;
            float sc = gg[col] * INV_STD;
            float bbc = bb[col], bec = be[col];
            int gc = col >> 3, cl = col & 7;
            #pragma unroll
            for (int m = 0; m < 4; ++m)
                #pragma unroll
                for (int r = 0; r < 4; ++r) {
                    int row = 64 * wm + 16 * m + 4 * lq + r;
                    float v = fmaxf((acc[m][n][r] + bbc) * sc + bec, 0.0f);
                    sh[row * 128 + ((gc ^ (row & 7)) << 3) + cl] = f2b(v);
                }
        }
    }
    #pragma unroll
    for (int p = 0; p < 8; ++p) {
        int idx = p * 256 + tid;
        *reinterpret_cast<int4*>(&sw[idx * 8]) = wreg[p];
    }
    __syncthreads();

    // ---- hidden layers: h(l+1) = relu(bn(h(l) @ W(l))) entirely in LDS ----
    for (int l = 0; l < NLAY; ++l) {
        if (l + 1 < NLAY) {   // preload next layer's weights; hides under MFMA
            const unsigned short* Wn = WTh + (size_t)((it * NLAY + l + 1) * 4 + g) * 128 * 128;
            #pragma unroll
            for (int p = 0; p < 8; ++p) {
                int idx = p * 256 + tid;
                int n = idx >> 4, gd = idx & 15;
                wreg[p] = *reinterpret_cast<const int4*>(Wn + n * 128 + ((gd ^ (n & 7)) << 3));
            }
        }
        #pragma unroll
        for (int m = 0; m < 4; ++m)
            #pragma unroll
            for (int n = 0; n < 4; ++n) acc[m][n] = zero4;
        #pragma unroll
        for (int kk = 0; kk < 4; ++kk) {
            bhalf8 af[4], bf[4];
            #pragma unroll
            for (int m = 0; m < 4; ++m) {
                int row = 64 * wm + 16 * m + lr;
                int gc = (4 * kk + lq) ^ (row & 7);
                af[m] = *reinterpret_cast<const bhalf8*>(&sh[row * 128 + (gc << 3)]);
            }
            #pragma unroll
            for (int n = 0; n < 4; ++n) {
                int nn = 64 * wn + 16 * n + lr;
                int gc = (4 * kk + lq) ^ (nn & 7);
                bf[n] = *reinterpret_cast<const bhalf8*>(&sw[nn * 128 + (gc << 3)]);
            }
            #pragma unroll
            for (int m = 0; m < 4; ++m)
                #pragma unroll
                for (int n = 0; n < 4; ++n)
                    acc[m][n] = __builtin_amdgcn_mfma_f32_16x16x32_bf16(af[m], bf[n], acc[m][n], 0, 0, 0);
        }
        if (l + 1 < NLAY) {
            __syncthreads();   // all reads of sh/sw done
            const int ilg = (it * NLAY + l) * 4 + g;
            const float* bb = bhp + (size_t)ilg * 128;
            const float* gg = ghp + (size_t)ilg * 128;
            const float* be = behp + (size_t)ilg * 128;
            #pragma unroll
            for (int n = 0; n < 4; ++n) {
                int col = 64 * wn + 16 * n + lr;
                float sc = gg[col] * INV_STD;
                float bbc = bb[col], bec = be[col];
                int gc = col >> 3, cl = col & 7;
                #pragma unroll
                for (int m = 0; m < 4; ++m)
                    #pragma unroll
                    for (int r = 0; r < 4; ++r) {
                        int row = 64 * wm + 16 * m + 4 * lq + r;
                        float v = fmaxf((acc[m][n][r] + bbc) * sc + bec, 0.0f);
                        sh[row * 128 + ((gc ^ (row & 7)) << 3) + cl] = f2b(v);
                    }
            }
            #pragma unroll
            for (int p = 0; p < 8; ++p) {
                int idx = p * 256 + tid;
                *reinterpret_cast<int4*>(&sw[idx * 8]) = wreg[p];
            }
            __syncthreads();
        }
    }

    // ---- scatter epilogue (layer NLAY-1 params; leaky_relu(relu(x)) == relu(x)) ----
    {
        const int ilg = (it * NLAY + (NLAY - 1)) * 4 + g;
        const float* bb = bhp + (size_t)ilg * 128;
        const float* gg = ghp + (size_t)ilg * 128;
        const float* be = behp + (size_t)ilg * 128;
        float attg = att[g];
        float scn[4], bbn[4], ben[4];
        int coln[4];
        #pragma unroll
        for (int n = 0; n < 4; ++n) {
            coln[n] = 64 * wn + 16 * n + lr;
            scn[n] = gg[coln[n]] * INV_STD;
            bbn[n] = bb[coln[n]];
            ben[n] = be[coln[n]];
        }
        #pragma unroll
        for (int m = 0; m < 4; ++m)
            #pragma unroll
            for (int r = 0; r < 4; ++r) {
                int row = r0 + 64 * wm + 16 * m + 4 * lq + r;
                int tt = rowmap[row];
                if (tt < 0) continue;
                int node = eidx[tt];  // i-index
                #pragma unroll
                for (int n = 0; n < 4; ++n) {
                    float v = fmaxf((acc[m][n][r] + bbn[n]) * scn[n] + ben[n], 0.0f);
                    atomicAdd(&nfout[(size_t)node * 128 + coln[n]], v * attg);
                }
            }
    }
}

// ---------------- nf fp32 -> bf16 ----------------

__global__ void cvt_k(const float* __restrict__ src, unsigned short* __restrict__ dst) {
    int i = blockIdx.x * 256 + threadIdx.x;  // over N*128/4
    float4 v = reinterpret_cast<const float4*>(src)[i];
    ushort4 o;
    o.x = f2b(v.x); o.y = f2b(v.y); o.z = f2b(v.z); o.w = f2b(v.w);
    reinterpret_cast<ushort4*>(dst)[i] = o;
}

// ---------------- pool + clamp ----------------

__global__ void pool_k(const float* __restrict__ nf4, const int* __restrict__ ntf,
                       float* __restrict__ emb) {
    int gid = blockIdx.x * 256 + threadIdx.x;  // over N*512
    int n = gid >> 9;
    int c = gid & 511;
    int grp = ntf[n];
    float v = nf4[(size_t)(c >> 7) * N_NODES * 128 + (size_t)n * 128 + (c & 127)];
    atomicAdd(&emb[(size_t)grp * 512 + c], v);
}

__global__ void clamp_k(const float* __restrict__ emb, float* __restrict__ out) {
    int i = blockIdx.x * 256 + threadIdx.x;
    out[i] = fminf(emb[i], 1.0e6f);
}

// ---------------- launch ----------------

extern "C" void kernel_launch(void* const* d_in, const int* in_sizes, int n_in,
                              void* d_out, int out_size, void* d_ws, size_t ws_size,
                              hipStream_t stream) {
    (void)in_sizes; (void)n_in; (void)out_size; (void)ws_size;
    const float* pos   = (const float*)d_in[0];
    const int*   eidx  = (const int*)d_in[1];
    const int*   edxjk = (const int*)d_in[2];
    const int*   edxij = (const int*)d_in[3];
    const int*   neip  = (const int*)d_in[4];
    const int*   ntf   = (const int*)d_in[5];
    const float* Wg    = (const float*)d_in[6];
    const float* bg    = (const float*)d_in[7];
    const float* gamg  = (const float*)d_in[8];
    const float* betg  = (const float*)d_in[9];
    const float* W0    = (const float*)d_in[10];
    const float* b0    = (const float*)d_in[11];
    const float* g0    = (const float*)d_in[12];
    const float* be0   = (const float*)d_in[13];
    const float* Wh    = (const float*)d_in[14];
    const float* bhp   = (const float*)d_in[15];
    const float* ghp   = (const float*)d_in[16];
    const float* behp  = (const float*)d_in[17];
    const float* att   = (const float*)d_in[18];

    char* w = (char*)d_ws;
    size_t off = 0;
    auto alloc = [&](size_t b) -> char* {
        char* p = w + off;
        off += (b + 255) & ~(size_t)255;
        return p;
    };
    int* ints            = (int*)alloc(256);                               // counts[4],cursor[4],aoff[5]
    int* rowmap          = (int*)alloc((size_t)RMAX * 4);
    unsigned short* WT0  = (unsigned short*)alloc((size_t)16 * 128 * 512 * 2);
    unsigned short* WTh  = (unsigned short*)alloc((size_t)64 * 128 * 128 * 2);
    unsigned short* geob = (unsigned short*)alloc((size_t)T_TRI * 128 * 2);
    unsigned short* nfb  = (unsigned short*)alloc((size_t)N_NODES * 128 * 2);
    float* nf4           = (float*)alloc((size_t)4 * N_NODES * 128 * 4);
    float* emb           = (float*)alloc((size_t)G_POOL * 512 * 4);

    hipMemsetAsync(ints, 0, 256, stream);
    hipMemsetAsync(rowmap, 0xFF, (size_t)RMAX * 4, stream);
    hipMemsetAsync(nf4, 0, (size_t)4 * N_NODES * 128 * 4, stream);
    hipMemsetAsync(emb, 0, (size_t)G_POOL * 512 * 4, stream);

    hist_k<<<256, 256, 0, stream>>>(edxjk, edxij, neip, ints);
    offsets_k<<<1, 1, 0, stream>>>(ints);
    scatter_k<<<256, 256, 0, stream>>>(edxjk, edxij, neip, ints, rowmap);
    t0_k<<<1024, 256, 0, stream>>>(W0, WT0);
    th_k<<<1024, 256, 0, stream>>>(Wh, WTh);
    geo_k<<<T_TRI / 2, 256, 0, stream>>>(pos, eidx, Wg, bg, gamg, betg, geob);

    for (int it = 0; it < NITER; ++it) {
        chain_k<<<MT, 256, 0, stream>>>(nfb, geob, eidx, rowmap, ints + 8, WT0, b0, g0, be0,
                                        WTh, bhp, ghp, behp, att,
                                        nf4 + (size_t)it * N_NODES * 128, it, it == 0 ? 1 : 0);
        cvt_k<<<2048, 256, 0, stream>>>(nf4 + (size_t)it * N_NODES * 128, nfb);
    }

    pool_k<<<32768, 256, 0, stream>>>(nf4, ntf, emb);
    clamp_k<<<1024, 256, 0, stream>>>(emb, (float*)d_out);
}

// Round 10
// 524.337 us; speedup vs baseline: 1.1576x; 1.1576x over previous
//
#include <hip/hip_runtime.h>
#include <hip/hip_bf16.h>
#include <math.h>

#define N_NODES 16384
#define T_TRI   65536
#define H_DIM   128
#define G_POOL  512
#define NITER   4
#define NLAY    4
#define RMAX    (T_TRI + 512)
#define MT      (RMAX / 128)      // 516 tiles of 128 rows

#define INV_STD 0.9999950000374996f

typedef __attribute__((ext_vector_type(8))) short bhalf8;
typedef __attribute__((ext_vector_type(4))) float f32x4;

__device__ __forceinline__ unsigned short f2b(float f) {
    unsigned int u = __float_as_uint(f);
    unsigned int r = (u + 0x7fffu + ((u >> 16) & 1u)) >> 16;
    return (unsigned short)r;
}
__device__ __forceinline__ float b2f(unsigned short b) {
    return __uint_as_float(((unsigned int)b) << 16);
}

// ---------------- group classification ----------------

__device__ __forceinline__ int group_of(int eij, int ejk, int nei) {
    return ((eij < nei) ? 0 : 2) + ((ejk < nei) ? 0 : 1);
}

// histogram over groups (ints[0..3]) AND over i-node (cnt[0..N-1])
__global__ void histboth_k(const int* __restrict__ edxjk, const int* __restrict__ edxij,
                           const int* __restrict__ neip, const int* __restrict__ eidx,
                           int* __restrict__ ints, int* __restrict__ cnt) {
    __shared__ int lc[4];
    if (threadIdx.x < 4) lc[threadIdx.x] = 0;
    __syncthreads();
    int t = blockIdx.x * 256 + threadIdx.x;
    int nei = *neip;
    int g = group_of(edxij[t], edxjk[t], nei);
    atomicAdd(&lc[g], 1);
    atomicAdd(&cnt[eidx[t]], 1);          // i-node histogram
    __syncthreads();
    if (threadIdx.x < 4) atomicAdd(&ints[threadIdx.x], lc[threadIdx.x]);
}

// group offsets (aoff) + exclusive scan of cnt -> row_start; cnt becomes cursor
__global__ void scanoff_k(int* __restrict__ ints, int* __restrict__ cnt,
                          int* __restrict__ row_start) {
    __shared__ int part[256];
    int tid = threadIdx.x;
    if (tid == 0) {
        int a = 0;
        ints[8] = 0;
        for (int g = 0; g < 4; ++g) {
            a = (a + ints[g] + 127) & ~127;
            ints[9 + g] = a;
        }
    }
    int base = tid * 64;
    int s = 0;
    for (int q = 0; q < 64; ++q) s += cnt[base + q];
    part[tid] = s;
    __syncthreads();
    if (tid == 0) {
        int run = 0;
        for (int q = 0; q < 256; ++q) { int v = part[q]; part[q] = run; run += v; }
        row_start[N_NODES] = run;
    }
    __syncthreads();
    int p = part[tid];
    for (int q = 0; q < 64; ++q) {
        int c = cnt[base + q];
        row_start[base + q] = p;
        cnt[base + q] = p;               // cursor
        p += c;
    }
}

// place triplets: rowmap[pos]=t (group-sorted) and row_ids[slot]=pos (i-sorted CSR)
__global__ void scatboth_k(const int* __restrict__ edxjk, const int* __restrict__ edxij,
                           const int* __restrict__ neip, const int* __restrict__ eidx,
                           int* __restrict__ ints, int* __restrict__ rowmap,
                           int* __restrict__ cursor, int* __restrict__ row_ids) {
    int t = blockIdx.x * 256 + threadIdx.x;
    int nei = *neip;
    int g = group_of(edxij[t], edxjk[t], nei);
    int lane = threadIdx.x & 63;
    unsigned long long msame = 0;
    #pragma unroll
    for (int q = 0; q < 4; ++q) {
        unsigned long long mq = __ballot(g == q);
        if (g == q) msame = mq;
    }
    int leader = __ffsll((long long)msame) - 1;
    int rank = __popcll(msame & ((1ull << lane) - 1ull));
    int base = 0;
    if (lane == leader) base = atomicAdd(&ints[4 + g], __popcll(msame));
    base = __shfl(base, leader);
    int pos = ints[8 + g] + base + rank;
    rowmap[pos] = t;
    int slot = atomicAdd(&cursor[eidx[t]], 1);
    row_ids[slot] = pos;
}

// ---------------- weight prep: LDS tile transpose, fp32 -> bf16 [n][k] ----------------

__global__ void t0_k(const float* __restrict__ W0, unsigned short* __restrict__ WT0) {
    __shared__ float t[32][33];
    int b = blockIdx.x;                 // 16 * 16 * 4 = 1024 tiles
    int ig = b >> 6;
    int kt = (b >> 2) & 15;
    int nt = b & 3;
    int tx = threadIdx.x & 31, ty = threadIdx.x >> 5;
    const float* src = W0 + ((size_t)ig * 512 + kt * 32) * 128 + nt * 32;
    #pragma unroll
    for (int q = 0; q < 4; ++q) { int r = q * 8 + ty; t[r][tx] = src[(size_t)r * 128 + tx]; }
    __syncthreads();
    unsigned short* dst = WT0 + ((size_t)ig * 128 + nt * 32) * 512 + kt * 32;
    #pragma unroll
    for (int q = 0; q < 4; ++q) { int r = q * 8 + ty; dst[(size_t)r * 512 + tx] = f2b(t[tx][r]); }
}

__global__ void th_k(const float* __restrict__ Wh, unsigned short* __restrict__ WTh) {
    __shared__ float t[32][33];
    int b = blockIdx.x;                 // 64 * 4 * 4 = 1024 tiles
    int ilg = b >> 4;
    int kt = (b >> 2) & 3;
    int nt = b & 3;
    int tx = threadIdx.x & 31, ty = threadIdx.x >> 5;
    const float* src = Wh + ((size_t)ilg * 128 + kt * 32) * 128 + nt * 32;
    #pragma unroll
    for (int q = 0; q < 4; ++q) { int r = q * 8 + ty; t[r][tx] = src[(size_t)r * 128 + tx]; }
    __syncthreads();
    unsigned short* dst = WTh + ((size_t)ilg * 128 + nt * 32) * 128 + kt * 32;
    #pragma unroll
    for (int q = 0; q < 4; ++q) { int r = q * 8 + ty; dst[(size_t)r * 128 + tx] = f2b(t[tx][r]); }
}

// ---------------- geo encoding ----------------

__global__ void geo_k(const float* __restrict__ pos, const int* __restrict__ eidx,
                      const float* __restrict__ Wg, const float* __restrict__ bg,
                      const float* __restrict__ gamg, const float* __restrict__ betg,
                      unsigned short* __restrict__ geob) {
    int t = blockIdx.x * 2 + (threadIdx.x >> 7);
    int h = threadIdx.x & 127;
    int ni = eidx[t], nj = eidx[T_TRI + t], nk = eidx[2 * T_TRI + t];
    float ix = pos[2 * ni], iy = pos[2 * ni + 1];
    float jx = pos[2 * nj], jy = pos[2 * nj + 1];
    float kx = pos[2 * nk], ky = pos[2 * nk + 1];
    float v1x = jx - ix, v1y = jy - iy;
    float v2x = kx - jx, v2y = ky - jy;
    float dij = sqrtf(v1x * v1x + v1y * v1y);
    float djk = sqrtf(v2x * v2x + v2y * v2y);
    float cr = v1x * v2y - v1y * v2x;
    float dt = v1x * v2x + v1y * v2y;
    float th = atan2f(fabsf(cr), dt);
    float v = dij * Wg[h] + djk * Wg[128 + h] + th * Wg[256 + h] + bg[h];
    v = v * (gamg[h] * INV_STD) + betg[h];
    v = fmaxf(v, 0.0f);
    geob[(size_t)t * 128 + h] = f2b(v);
}

// ---------------- fused per-interaction chain: GEMM0 + 4 hidden + h_final store ----------------

template<int SKIPNF>
__global__ __launch_bounds__(256, 2) void chain_k(
    const unsigned short* __restrict__ nfb, const unsigned short* __restrict__ geob,
    const int* __restrict__ eidx, const int* __restrict__ rowmap,
    const int* __restrict__ aoff, const unsigned short* __restrict__ WT0,
    const float* __restrict__ b0, const float* __restrict__ g0, const float* __restrict__ be0,
    const unsigned short* __restrict__ WTh,
    const float* __restrict__ bhp, const float* __restrict__ ghp, const float* __restrict__ behp,
    const float* __restrict__ att, unsigned short* __restrict__ hfinal,
    int it) {
    __shared__ unsigned short sh[128 * 128];   // 32 KB h tile  [row][k] swizzled
    __shared__ unsigned short sw[128 * 128];   // 32 KB W tile  [n][k] swizzled; GEMM0: As+Bs
    unsigned short* As = sw;                   // [128*64]
    unsigned short* Bs = sw + 128 * 64;        // [128*64]

    const int r0 = blockIdx.x * 128;
    int g = 0;
    if (r0 >= aoff[1]) g = 1;
    if (r0 >= aoff[2]) g = 2;
    if (r0 >= aoff[3]) g = 3;
    const int tid = threadIdx.x;
    const int lane = tid & 63;
    const int wid = tid >> 6;
    const int wm = wid >> 1, wn = wid & 1;
    const int lr = lane & 15, lq = lane >> 4;

    // ---- hoisted gather indices: this thread stages rows p*32 + tid/8 ----
    const int myrow = tid >> 3;
    const int mycolb = (tid & 7) * 8;      // element offset within 64-wide chunk
    int ttv[4], offi[4], offj[4], offk2[4], offt[4];
    #pragma unroll
    for (int p = 0; p < 4; ++p) {
        int row = p * 32 + myrow;
        int tt = rowmap[r0 + row];
        ttv[p] = tt;
        int ts = tt < 0 ? 0 : tt;
        offt[p] = ts * 128;
        if (!SKIPNF) {
            offi[p]  = eidx[ts] * 128;
            offj[p]  = eidx[T_TRI + ts] * 128;
            offk2[p] = eidx[2 * T_TRI + ts] * 128;
        }
    }

    f32x4 acc[4][4];
    const f32x4 zero4 = {0.f, 0.f, 0.f, 0.f};
    #pragma unroll
    for (int m = 0; m < 4; ++m)
        #pragma unroll
        for (int n = 0; n < 4; ++n) acc[m][n] = zero4;

    // ---- phase 0: GEMM0  [128 gathered rows, K=512] x [512,128] ----
    const unsigned short* Wt = WT0 + (size_t)(it * 4 + g) * 128 * 512;
    #pragma unroll
    for (int k0 = (SKIPNF ? 384 : 0); k0 < 512; k0 += 64) {
        const int region = k0 >> 7;   // 0:nf[i] 1:nf[j] 2:nf[k] 3:geo
        const int half = k0 & 127;
        #pragma unroll
        for (int p = 0; p < 4; ++p) {
            int row = p * 32 + myrow;
            int4 v = {0, 0, 0, 0};
            if (ttv[p] >= 0) {
                const unsigned short* src =
                    region == 0 ? nfb + offi[p] :
                    region == 1 ? nfb + offj[p] :
                    region == 2 ? nfb + offk2[p] :
                                  geob + offt[p];
                v = *reinterpret_cast<const int4*>(src + half + mycolb);
            }
            *reinterpret_cast<int4*>(&As[row * 64 + (((tid & 7) ^ (row & 7)) << 3)]) = v;
        }
        #pragma unroll
        for (int p = 0; p < 4; ++p) {
            int n = p * 32 + myrow;
            int4 v = *reinterpret_cast<const int4*>(Wt + (size_t)n * 512 + k0 + mycolb);
            *reinterpret_cast<int4*>(&Bs[n * 64 + (((tid & 7) ^ (n & 7)) << 3)]) = v;
        }
        __syncthreads();
        #pragma unroll
        for (int ks = 0; ks < 2; ++ks) {
            bhalf8 af[4], bf[4];
            #pragma unroll
            for (int m = 0; m < 4; ++m) {
                int row = 64 * wm + 16 * m + lr;
                int c8 = (4 * ks + lq) ^ (row & 7);
                af[m] = *reinterpret_cast<const bhalf8*>(&As[row * 64 + (c8 << 3)]);
            }
            #pragma unroll
            for (int n = 0; n < 4; ++n) {
                int nn = 64 * wn + 16 * n + lr;
                int c8 = (4 * ks + lq) ^ (nn & 7);
                bf[n] = *reinterpret_cast<const bhalf8*>(&Bs[nn * 64 + (c8 << 3)]);
            }
            #pragma unroll
            for (int m = 0; m < 4; ++m)
                #pragma unroll
                for (int n = 0; n < 4; ++n)
                    acc[m][n] = __builtin_amdgcn_mfma_f32_16x16x32_bf16(af[m], bf[n], acc[m][n], 0, 0, 0);
        }
        __syncthreads();   // final iter: all waves done with sw
    }

    int4 wreg[8];
    // preload W^0 (issues early; latency hides under epilogue VALU)
    {
        const unsigned short* Wl = WTh + (size_t)((it * NLAY + 0) * 4 + g) * 128 * 128;
        #pragma unroll
        for (int p = 0; p < 8; ++p) {
            int idx = p * 256 + tid;
            int n = idx >> 4, gd = idx & 15;
            wreg[p] = *reinterpret_cast<const int4*>(Wl + n * 128 + ((gd ^ (n & 7)) << 3));
        }
    }
    // h0 = relu(bn(acc)) -> sh (swizzled granules)
    {
        const float* bb = b0 + (it * 4 + g) * 128;
        const float* gg = g0 + (it * 4 + g) * 128;
        const float* be = be0 + (it * 4 + g) * 128;
        #pragma unroll
        for (int n = 0; n < 4; ++n) {
            int col = 64 * wn + 16 * n + lr;
            float sc = gg[col] * INV_STD;
            float bbc = bb[col], bec = be[col];
            int gc = col >> 3, cl = col & 7;
            #pragma unroll
            for (int m = 0; m < 4; ++m)
                #pragma unroll
                for (int r = 0; r < 4; ++r) {
                    int row = 64 * wm + 16 * m + 4 * lq + r;
                    float v = fmaxf((acc[m][n][r] + bbc) * sc + bec, 0.0f);
                    sh[row * 128 + ((gc ^ (row & 7)) << 3) + cl] = f2b(v);
                }
        }
    }
    #pragma unroll
    for (int p = 0; p < 8; ++p) {
        int idx = p * 256 + tid;
        *reinterpret_cast<int4*>(&sw[idx * 8]) = wreg[p];
    }
    __syncthreads();

    // ---- hidden layers: h(l+1) = relu(bn(h(l) @ W(l))) entirely in LDS ----
    for (int l = 0; l < NLAY; ++l) {
        if (l + 1 < NLAY) {
            const unsigned short* Wn = WTh + (size_t)((it * NLAY + l + 1) * 4 + g) * 128 * 128;
            #pragma unroll
            for (int p = 0; p < 8; ++p) {
                int idx = p * 256 + tid;
                int n = idx >> 4, gd = idx & 15;
                wreg[p] = *reinterpret_cast<const int4*>(Wn + n * 128 + ((gd ^ (n & 7)) << 3));
            }
        }
        #pragma unroll
        for (int m = 0; m < 4; ++m)
            #pragma unroll
            for (int n = 0; n < 4; ++n) acc[m][n] = zero4;
        #pragma unroll
        for (int kk = 0; kk < 4; ++kk) {
            bhalf8 af[4], bf[4];
            #pragma unroll
            for (int m = 0; m < 4; ++m) {
                int row = 64 * wm + 16 * m + lr;
                int gc = (4 * kk + lq) ^ (row & 7);
                af[m] = *reinterpret_cast<const bhalf8*>(&sh[row * 128 + (gc << 3)]);
            }
            #pragma unroll
            for (int n = 0; n < 4; ++n) {
                int nn = 64 * wn + 16 * n + lr;
                int gc = (4 * kk + lq) ^ (nn & 7);
                bf[n] = *reinterpret_cast<const bhalf8*>(&sw[nn * 128 + (gc << 3)]);
            }
            #pragma unroll
            for (int m = 0; m < 4; ++m)
                #pragma unroll
                for (int n = 0; n < 4; ++n)
                    acc[m][n] = __builtin_amdgcn_mfma_f32_16x16x32_bf16(af[m], bf[n], acc[m][n], 0, 0, 0);
        }
        if (l + 1 < NLAY) {
            __syncthreads();
            const int ilg = (it * NLAY + l) * 4 + g;
            const float* bb = bhp + (size_t)ilg * 128;
            const float* gg = ghp + (size_t)ilg * 128;
            const float* be = behp + (size_t)ilg * 128;
            #pragma unroll
            for (int n = 0; n < 4; ++n) {
                int col = 64 * wn + 16 * n + lr;
                float sc = gg[col] * INV_STD;
                float bbc = bb[col], bec = be[col];
                int gc = col >> 3, cl = col & 7;
                #pragma unroll
                for (int m = 0; m < 4; ++m)
                    #pragma unroll
                    for (int r = 0; r < 4; ++r) {
                        int row = 64 * wm + 16 * m + 4 * lq + r;
                        float v = fmaxf((acc[m][n][r] + bbc) * sc + bec, 0.0f);
                        sh[row * 128 + ((gc ^ (row & 7)) << 3) + cl] = f2b(v);
                    }
            }
            #pragma unroll
            for (int p = 0; p < 8; ++p) {
                int idx = p * 256 + tid;
                *reinterpret_cast<int4*>(&sw[idx * 8]) = wreg[p];
            }
            __syncthreads();
        }
    }

    // ---- store epilogue: hfinal = att * relu(bn(acc))  (streaming, no atomics) ----
    {
        const int ilg = (it * NLAY + (NLAY - 1)) * 4 + g;
        const float* bb = bhp + (size_t)ilg * 128;
        const float* gg = ghp + (size_t)ilg * 128;
        const float* be = behp + (size_t)ilg * 128;
        float attg = att[g];
        #pragma unroll
        for (int n = 0; n < 4; ++n) {
            int col = 64 * wn + 16 * n + lr;
            float sc = gg[col] * INV_STD;
            float bbc = bb[col], bec = be[col];
            #pragma unroll
            for (int m = 0; m < 4; ++m)
                #pragma unroll
                for (int r = 0; r < 4; ++r) {
                    int row = r0 + 64 * wm + 16 * m + 4 * lq + r;
                    float v = fmaxf((acc[m][n][r] + bbc) * sc + bec, 0.0f) * attg;
                    hfinal[(size_t)row * 128 + col] = f2b(v);
                }
        }
    }
}

// ---------------- per-node CSR reduce: nf = segment_sum; fused nfb cvt + pool ----------------

__global__ void reduce_k(const unsigned short* __restrict__ hfinal,
                         const int* __restrict__ row_start, const int* __restrict__ row_ids,
                         const int* __restrict__ ntf, unsigned short* __restrict__ nfb,
                         float* __restrict__ emb, int itoff) {
    int n = blockIdx.x * 2 + (threadIdx.x >> 7);
    int c = threadIdx.x & 127;
    int s = row_start[n], e = row_start[n + 1];
    float acc = 0.0f;
    for (int r = s; r < e; ++r) {
        int rid = row_ids[r];
        acc += b2f(hfinal[(size_t)rid * 128 + c]);
    }
    nfb[(size_t)n * 128 + c] = f2b(acc);
    atomicAdd(&emb[(size_t)ntf[n] * 512 + itoff + c], acc);
}

__global__ void clamp_k(const float* __restrict__ emb, float* __restrict__ out) {
    int i = blockIdx.x * 256 + threadIdx.x;
    out[i] = fminf(emb[i], 1.0e6f);
}

// ---------------- launch ----------------

extern "C" void kernel_launch(void* const* d_in, const int* in_sizes, int n_in,
                              void* d_out, int out_size, void* d_ws, size_t ws_size,
                              hipStream_t stream) {
    (void)in_sizes; (void)n_in; (void)out_size; (void)ws_size;
    const float* pos   = (const float*)d_in[0];
    const int*   eidx  = (const int*)d_in[1];
    const int*   edxjk = (const int*)d_in[2];
    const int*   edxij = (const int*)d_in[3];
    const int*   neip  = (const int*)d_in[4];
    const int*   ntf   = (const int*)d_in[5];
    const float* Wg    = (const float*)d_in[6];
    const float* bg    = (const float*)d_in[7];
    const float* gamg  = (const float*)d_in[8];
    const float* betg  = (const float*)d_in[9];
    const float* W0    = (const float*)d_in[10];
    const float* b0    = (const float*)d_in[11];
    const float* g0    = (const float*)d_in[12];
    const float* be0   = (const float*)d_in[13];
    const float* Wh    = (const float*)d_in[14];
    const float* bhp   = (const float*)d_in[15];
    const float* ghp   = (const float*)d_in[16];
    const float* behp  = (const float*)d_in[17];
    const float* att   = (const float*)d_in[18];

    char* w = (char*)d_ws;
    size_t off = 0;
    auto alloc = [&](size_t b) -> char* {
        char* p = w + off;
        off += (b + 255) & ~(size_t)255;
        return p;
    };
    int* ints            = (int*)alloc(256);                         // counts[4],cursor[4],aoff[5]
    int* rowmap          = (int*)alloc((size_t)RMAX * 4);
    int* cnt             = (int*)alloc((size_t)N_NODES * 4);         // i-hist -> cursor
    int* row_start       = (int*)alloc((size_t)(N_NODES + 1) * 4);
    int* row_ids         = (int*)alloc((size_t)T_TRI * 4);
    unsigned short* WT0  = (unsigned short*)alloc((size_t)16 * 128 * 512 * 2);
    unsigned short* WTh  = (unsigned short*)alloc((size_t)64 * 128 * 128 * 2);
    unsigned short* geob = (unsigned short*)alloc((size_t)T_TRI * 128 * 2);
    unsigned short* nfb  = (unsigned short*)alloc((size_t)N_NODES * 128 * 2);
    unsigned short* hfin = (unsigned short*)alloc((size_t)RMAX * 128 * 2);
    float* emb           = (float*)alloc((size_t)G_POOL * 512 * 4);

    hipMemsetAsync(ints, 0, 256, stream);
    hipMemsetAsync(rowmap, 0xFF, (size_t)RMAX * 4, stream);
    hipMemsetAsync(cnt, 0, (size_t)N_NODES * 4, stream);
    hipMemsetAsync(emb, 0, (size_t)G_POOL * 512 * 4, stream);

    histboth_k<<<256, 256, 0, stream>>>(edxjk, edxij, neip, eidx, ints, cnt);
    scanoff_k<<<1, 256, 0, stream>>>(ints, cnt, row_start);
    scatboth_k<<<256, 256, 0, stream>>>(edxjk, edxij, neip, eidx, ints, rowmap, cnt, row_ids);
    t0_k<<<1024, 256, 0, stream>>>(W0, WT0);
    th_k<<<1024, 256, 0, stream>>>(Wh, WTh);
    geo_k<<<T_TRI / 2, 256, 0, stream>>>(pos, eidx, Wg, bg, gamg, betg, geob);

    for (int it = 0; it < NITER; ++it) {
        if (it == 0)
            chain_k<1><<<MT, 256, 0, stream>>>(nfb, geob, eidx, rowmap, ints + 8, WT0, b0, g0, be0,
                                               WTh, bhp, ghp, behp, att, hfin, it);
        else
            chain_k<0><<<MT, 256, 0, stream>>>(nfb, geob, eidx, rowmap, ints + 8, WT0, b0, g0, be0,
                                               WTh, bhp, ghp, behp, att, hfin, it);
        reduce_k<<<N_NODES / 2, 256, 0, stream>>>(hfin, row_start, row_ids, ntf, nfb, emb, it * 128);
    }

    clamp_k<<<1024, 256, 0, stream>>>(emb, (float*)d_out);
}

// Round 11
// 488.470 us; speedup vs baseline: 1.2426x; 1.0734x over previous
//
#include <hip/hip_runtime.h>
#include <hip/hip_bf16.h>
#include <math.h>

#define N_NODES 16384
#define T_TRI   65536
#define H_DIM   128
#define G_POOL  512
#define NITER   4
#define NLAY    4
#define RMAX    (T_TRI + 512)
#define MT      (RMAX / 128)      // 516 tiles of 128 rows

#define INV_STD 0.9999950000374996f

typedef __attribute__((ext_vector_type(8))) short bhalf8;
typedef __attribute__((ext_vector_type(4))) float f32x4;

__device__ __forceinline__ unsigned short f2b(float f) {
    unsigned int u = __float_as_uint(f);
    unsigned int r = (u + 0x7fffu + ((u >> 16) & 1u)) >> 16;
    return (unsigned short)r;
}
__device__ __forceinline__ float b2f(unsigned short b) {
    return __uint_as_float(((unsigned int)b) << 16);
}

// ---------------- group classification ----------------

__device__ __forceinline__ int group_of(int eij, int ejk, int nei) {
    return ((eij < nei) ? 0 : 2) + ((ejk < nei) ? 0 : 1);
}

// histogram over groups (ints[0..3]) AND over i-node (cnt[0..N-1])
__global__ void histboth_k(const int* __restrict__ edxjk, const int* __restrict__ edxij,
                           const int* __restrict__ neip, const int* __restrict__ eidx,
                           int* __restrict__ ints, int* __restrict__ cnt) {
    __shared__ int lc[4];
    if (threadIdx.x < 4) lc[threadIdx.x] = 0;
    __syncthreads();
    int t = blockIdx.x * 256 + threadIdx.x;
    int nei = *neip;
    int g = group_of(edxij[t], edxjk[t], nei);
    atomicAdd(&lc[g], 1);
    atomicAdd(&cnt[eidx[t]], 1);          // i-node histogram
    __syncthreads();
    if (threadIdx.x < 4) atomicAdd(&ints[threadIdx.x], lc[threadIdx.x]);
}

// group offsets (aoff) + exclusive scan of cnt -> row_start; cnt becomes cursor
__global__ void scanoff_k(int* __restrict__ ints, int* __restrict__ cnt,
                          int* __restrict__ row_start) {
    __shared__ int part[256];
    int tid = threadIdx.x;
    if (tid == 0) {
        int a = 0;
        ints[8] = 0;
        for (int g = 0; g < 4; ++g) {
            a = (a + ints[g] + 127) & ~127;
            ints[9 + g] = a;
        }
    }
    int base = tid * 64;
    int s = 0;
    for (int q = 0; q < 64; ++q) s += cnt[base + q];
    part[tid] = s;
    __syncthreads();
    if (tid == 0) {
        int run = 0;
        for (int q = 0; q < 256; ++q) { int v = part[q]; part[q] = run; run += v; }
        row_start[N_NODES] = run;
    }
    __syncthreads();
    int p = part[tid];
    for (int q = 0; q < 64; ++q) {
        int c = cnt[base + q];
        row_start[base + q] = p;
        cnt[base + q] = p;               // cursor
        p += c;
    }
}

// place triplets: rowmap[pos]=t (group-sorted) and row_ids[slot]=pos (i-sorted CSR)
__global__ void scatboth_k(const int* __restrict__ edxjk, const int* __restrict__ edxij,
                           const int* __restrict__ neip, const int* __restrict__ eidx,
                           int* __restrict__ ints, int* __restrict__ rowmap,
                           int* __restrict__ cursor, int* __restrict__ row_ids) {
    int t = blockIdx.x * 256 + threadIdx.x;
    int nei = *neip;
    int g = group_of(edxij[t], edxjk[t], nei);
    int lane = threadIdx.x & 63;
    unsigned long long msame = 0;
    #pragma unroll
    for (int q = 0; q < 4; ++q) {
        unsigned long long mq = __ballot(g == q);
        if (g == q) msame = mq;
    }
    int leader = __ffsll((long long)msame) - 1;
    int rank = __popcll(msame & ((1ull << lane) - 1ull));
    int base = 0;
    if (lane == leader) base = atomicAdd(&ints[4 + g], __popcll(msame));
    base = __shfl(base, leader);
    int pos = ints[8 + g] + base + rank;
    rowmap[pos] = t;
    int slot = atomicAdd(&cursor[eidx[t]], 1);
    row_ids[slot] = pos;
}

// ---------------- weight prep: LDS tile transpose, fp32 -> bf16 [n][k] ----------------

__global__ void t0_k(const float* __restrict__ W0, unsigned short* __restrict__ WT0) {
    __shared__ float t[32][33];
    int b = blockIdx.x;                 // 16 * 16 * 4 = 1024 tiles
    int ig = b >> 6;
    int kt = (b >> 2) & 15;
    int nt = b & 3;
    int tx = threadIdx.x & 31, ty = threadIdx.x >> 5;
    const float* src = W0 + ((size_t)ig * 512 + kt * 32) * 128 + nt * 32;
    #pragma unroll
    for (int q = 0; q < 4; ++q) { int r = q * 8 + ty; t[r][tx] = src[(size_t)r * 128 + tx]; }
    __syncthreads();
    unsigned short* dst = WT0 + ((size_t)ig * 128 + nt * 32) * 512 + kt * 32;
    #pragma unroll
    for (int q = 0; q < 4; ++q) { int r = q * 8 + ty; dst[(size_t)r * 512 + tx] = f2b(t[tx][r]); }
}

__global__ void th_k(const float* __restrict__ Wh, unsigned short* __restrict__ WTh) {
    __shared__ float t[32][33];
    int b = blockIdx.x;                 // 64 * 4 * 4 = 1024 tiles
    int ilg = b >> 4;
    int kt = (b >> 2) & 3;
    int nt = b & 3;
    int tx = threadIdx.x & 31, ty = threadIdx.x >> 5;
    const float* src = Wh + ((size_t)ilg * 128 + kt * 32) * 128 + nt * 32;
    #pragma unroll
    for (int q = 0; q < 4; ++q) { int r = q * 8 + ty; t[r][tx] = src[(size_t)r * 128 + tx]; }
    __syncthreads();
    unsigned short* dst = WTh + ((size_t)ilg * 128 + nt * 32) * 128 + kt * 32;
    #pragma unroll
    for (int q = 0; q < 4; ++q) { int r = q * 8 + ty; dst[(size_t)r * 128 + tx] = f2b(t[tx][r]); }
}

// ---------------- geo encoding (vectorized: 8 cols/thread, int4 store) ----------------

__global__ void geo_k(const float* __restrict__ pos, const int* __restrict__ eidx,
                      const float* __restrict__ Wg, const float* __restrict__ bg,
                      const float* __restrict__ gamg, const float* __restrict__ betg,
                      unsigned short* __restrict__ geob) {
    int t = blockIdx.x * 16 + (threadIdx.x >> 4);
    int h0 = (threadIdx.x & 15) * 8;
    int ni = eidx[t], nj = eidx[T_TRI + t], nk = eidx[2 * T_TRI + t];
    float ix = pos[2 * ni], iy = pos[2 * ni + 1];
    float jx = pos[2 * nj], jy = pos[2 * nj + 1];
    float kx = pos[2 * nk], ky = pos[2 * nk + 1];
    float v1x = jx - ix, v1y = jy - iy;
    float v2x = kx - jx, v2y = ky - jy;
    float dij = sqrtf(v1x * v1x + v1y * v1y);
    float djk = sqrtf(v2x * v2x + v2y * v2y);
    float cr = v1x * v2y - v1y * v2x;
    float dt = v1x * v2x + v1y * v2y;
    float th = atan2f(fabsf(cr), dt);
    unsigned int ov[4];
    #pragma unroll
    for (int q = 0; q < 4; ++q) {
        unsigned int lo, hi;
        #pragma unroll
        for (int e = 0; e < 2; ++e) {
            int h = h0 + q * 2 + e;
            float v = dij * Wg[h] + djk * Wg[128 + h] + th * Wg[256 + h] + bg[h];
            v = v * (gamg[h] * INV_STD) + betg[h];
            v = fmaxf(v, 0.0f);
            if (e == 0) lo = f2b(v); else hi = f2b(v);
        }
        ov[q] = lo | (hi << 16);
    }
    int4 o = { (int)ov[0], (int)ov[1], (int)ov[2], (int)ov[3] };
    *reinterpret_cast<int4*>(&geob[(size_t)t * 128 + h0]) = o;
}

// ---------------- fused per-interaction chain: GEMM0 + 4 hidden + h_final store ----------------

template<int SKIPNF>
__global__ __launch_bounds__(256, 2) void chain_k(
    const unsigned short* __restrict__ nfb, const unsigned short* __restrict__ geob,
    const int* __restrict__ eidx, const int* __restrict__ rowmap,
    const int* __restrict__ aoff, const unsigned short* __restrict__ WT0,
    const float* __restrict__ b0, const float* __restrict__ g0, const float* __restrict__ be0,
    const unsigned short* __restrict__ WTh,
    const float* __restrict__ bhp, const float* __restrict__ ghp, const float* __restrict__ behp,
    const float* __restrict__ att, unsigned short* __restrict__ hfinal,
    int it) {
    __shared__ unsigned short sh[128 * 128];   // 32 KB: GEMM0 buf1 (As|Bs); later h tile
    __shared__ unsigned short sw[128 * 128];   // 32 KB: GEMM0 buf0 (As|Bs); later W tile

    const int r0 = blockIdx.x * 128;
    int g = 0;
    if (r0 >= aoff[1]) g = 1;
    if (r0 >= aoff[2]) g = 2;
    if (r0 >= aoff[3]) g = 3;
    const int tid = threadIdx.x;
    const int lane = tid & 63;
    const int wid = tid >> 6;
    const int wm = wid >> 1, wn = wid & 1;
    const int lr = lane & 15, lq = lane >> 4;

    // ---- hoisted gather indices: this thread stages rows p*32 + tid/8 ----
    const int myrow = tid >> 3;
    const int mycolb = (tid & 7) * 8;      // element offset within 64-wide chunk
    int ttv[4], offi[4], offj[4], offk2[4], offt[4];
    #pragma unroll
    for (int p = 0; p < 4; ++p) {
        int row = p * 32 + myrow;
        int tt = rowmap[r0 + row];
        ttv[p] = tt;
        int ts = tt < 0 ? 0 : tt;
        offt[p] = ts * 128;
        if (!SKIPNF) {
            offi[p]  = eidx[ts] * 128;
            offj[p]  = eidx[T_TRI + ts] * 128;
            offk2[p] = eidx[2 * T_TRI + ts] * 128;
        }
    }

    f32x4 acc[4][4];
    const f32x4 zero4 = {0.f, 0.f, 0.f, 0.f};
    #pragma unroll
    for (int m = 0; m < 4; ++m)
        #pragma unroll
        for (int n = 0; n < 4; ++n) acc[m][n] = zero4;

    // ---- phase 0: GEMM0 [128 gathered rows, K=512] x [512,128], ping-pong sw/sh ----
    const unsigned short* Wt = WT0 + (size_t)(it * 4 + g) * 128 * 512;
    constexpr int KSTEPS = SKIPNF ? 2 : 8;
    constexpr int KBASE  = SKIPNF ? 384 : 0;
    unsigned short* bufs[2] = { sw, sh };
    int4 ra[4], rb[4];

    // prologue: stage first k-step into buf0
    {
        const int k0 = KBASE;
        const int region = k0 >> 7, half = k0 & 127;
        #pragma unroll
        for (int p = 0; p < 4; ++p) {
            int4 v = {0, 0, 0, 0};
            if (ttv[p] >= 0) {
                const unsigned short* src =
                    region == 0 ? nfb + offi[p] :
                    region == 1 ? nfb + offj[p] :
                    region == 2 ? nfb + offk2[p] :
                                  geob + offt[p];
                v = *reinterpret_cast<const int4*>(src + half + mycolb);
            }
            ra[p] = v;
            rb[p] = *reinterpret_cast<const int4*>(Wt + (size_t)(p * 32 + myrow) * 512 + k0 + mycolb);
        }
        #pragma unroll
        for (int p = 0; p < 4; ++p) {
            int row = p * 32 + myrow;
            int sz = (((tid & 7) ^ (row & 7)) << 3);
            *reinterpret_cast<int4*>(&bufs[0][row * 64 + sz]) = ra[p];
            *reinterpret_cast<int4*>(&bufs[0][128 * 64 + row * 64 + sz]) = rb[p];
        }
        __syncthreads();
    }

    #pragma unroll
    for (int s = 0; s < KSTEPS; ++s) {
        const int cur = s & 1;
        if (s + 1 < KSTEPS) {    // issue next k-step's loads (overlap with MFMA below)
            const int k1 = KBASE + (s + 1) * 64;
            const int region = k1 >> 7, half = k1 & 127;
            #pragma unroll
            for (int p = 0; p < 4; ++p) {
                int4 v = {0, 0, 0, 0};
                if (ttv[p] >= 0) {
                    const unsigned short* src =
                        region == 0 ? nfb + offi[p] :
                        region == 1 ? nfb + offj[p] :
                        region == 2 ? nfb + offk2[p] :
                                      geob + offt[p];
                    v = *reinterpret_cast<const int4*>(src + half + mycolb);
                }
                ra[p] = v;
                rb[p] = *reinterpret_cast<const int4*>(Wt + (size_t)(p * 32 + myrow) * 512 + k1 + mycolb);
            }
        }
        const unsigned short* Ab = bufs[cur];
        const unsigned short* Bb = bufs[cur] + 128 * 64;
        #pragma unroll
        for (int ks = 0; ks < 2; ++ks) {
            bhalf8 af[4], bf[4];
            #pragma unroll
            for (int m = 0; m < 4; ++m) {
                int row = 64 * wm + 16 * m + lr;
                int c8 = (4 * ks + lq) ^ (row & 7);
                af[m] = *reinterpret_cast<const bhalf8*>(&Ab[row * 64 + (c8 << 3)]);
            }
            #pragma unroll
            for (int n = 0; n < 4; ++n) {
                int nn = 64 * wn + 16 * n + lr;
                int c8 = (4 * ks + lq) ^ (nn & 7);
                bf[n] = *reinterpret_cast<const bhalf8*>(&Bb[nn * 64 + (c8 << 3)]);
            }
            #pragma unroll
            for (int m = 0; m < 4; ++m)
                #pragma unroll
                for (int n = 0; n < 4; ++n)
                    acc[m][n] = __builtin_amdgcn_mfma_f32_16x16x32_bf16(af[m], bf[n], acc[m][n], 0, 0, 0);
        }
        if (s + 1 < KSTEPS) {    // write prefetch into the other buffer
            unsigned short* An = bufs[cur ^ 1];
            #pragma unroll
            for (int p = 0; p < 4; ++p) {
                int row = p * 32 + myrow;
                int sz = (((tid & 7) ^ (row & 7)) << 3);
                *reinterpret_cast<int4*>(&An[row * 64 + sz]) = ra[p];
                *reinterpret_cast<int4*>(&An[128 * 64 + row * 64 + sz]) = rb[p];
            }
        }
        __syncthreads();
    }

    int4 wreg[8];
    // preload W^0 (issues early; latency hides under epilogue VALU)
    {
        const unsigned short* Wl = WTh + (size_t)((it * NLAY + 0) * 4 + g) * 128 * 128;
        #pragma unroll
        for (int p = 0; p < 8; ++p) {
            int idx = p * 256 + tid;
            int n = idx >> 4, gd = idx & 15;
            wreg[p] = *reinterpret_cast<const int4*>(Wl + n * 128 + ((gd ^ (n & 7)) << 3));
        }
    }
    // h0 = relu(bn(acc)) -> sh (swizzled granules)
    {
        const float* bb = b0 + (it * 4 + g) * 128;
        const float* gg = g0 + (it * 4 + g) * 128;
        const float* be = be0 + (it * 4 + g) * 128;
        #pragma unroll
        for (int n = 0; n < 4; ++n) {
            int col = 64 * wn + 16 * n + lr;
            float sc = gg[col] * INV_STD;
            float bbc = bb[col], bec = be[col];
            int gc = col >> 3, cl = col & 7;
            #pragma unroll
            for (int m = 0; m < 4; ++m)
                #pragma unroll
                for (int r = 0; r < 4; ++r) {
                    int row = 64 * wm + 16 * m + 4 * lq + r;
                    float v = fmaxf((acc[m][n][r] + bbc) * sc + bec, 0.0f);
                    sh[row * 128 + ((gc ^ (row & 7)) << 3) + cl] = f2b(v);
                }
        }
    }
    #pragma unroll
    for (int p = 0; p < 8; ++p) {
        int idx = p * 256 + tid;
        *reinterpret_cast<int4*>(&sw[idx * 8]) = wreg[p];
    }
    __syncthreads();

    // ---- hidden layers: h(l+1) = relu(bn(h(l) @ W(l))) entirely in LDS ----
    for (int l = 0; l < NLAY; ++l) {
        if (l + 1 < NLAY) {
            const unsigned short* Wn = WTh + (size_t)((it * NLAY + l + 1) * 4 + g) * 128 * 128;
            #pragma unroll
            for (int p = 0; p < 8; ++p) {
                int idx = p * 256 + tid;
                int n = idx >> 4, gd = idx & 15;
                wreg[p] = *reinterpret_cast<const int4*>(Wn + n * 128 + ((gd ^ (n & 7)) << 3));
            }
        }
        #pragma unroll
        for (int m = 0; m < 4; ++m)
            #pragma unroll
            for (int n = 0; n < 4; ++n) acc[m][n] = zero4;
        #pragma unroll
        for (int kk = 0; kk < 4; ++kk) {
            bhalf8 af[4], bf[4];
            #pragma unroll
            for (int m = 0; m < 4; ++m) {
                int row = 64 * wm + 16 * m + lr;
                int gc = (4 * kk + lq) ^ (row & 7);
                af[m] = *reinterpret_cast<const bhalf8*>(&sh[row * 128 + (gc << 3)]);
            }
            #pragma unroll
            for (int n = 0; n < 4; ++n) {
                int nn = 64 * wn + 16 * n + lr;
                int gc = (4 * kk + lq) ^ (nn & 7);
                bf[n] = *reinterpret_cast<const bhalf8*>(&sw[nn * 128 + (gc << 3)]);
            }
            #pragma unroll
            for (int m = 0; m < 4; ++m)
                #pragma unroll
                for (int n = 0; n < 4; ++n)
                    acc[m][n] = __builtin_amdgcn_mfma_f32_16x16x32_bf16(af[m], bf[n], acc[m][n], 0, 0, 0);
        }
        if (l + 1 < NLAY) {
            __syncthreads();
            const int ilg = (it * NLAY + l) * 4 + g;
            const float* bb = bhp + (size_t)ilg * 128;
            const float* gg = ghp + (size_t)ilg * 128;
            const float* be = behp + (size_t)ilg * 128;
            #pragma unroll
            for (int n = 0; n < 4; ++n) {
                int col = 64 * wn + 16 * n + lr;
                float sc = gg[col] * INV_STD;
                float bbc = bb[col], bec = be[col];
                int gc = col >> 3, cl = col & 7;
                #pragma unroll
                for (int m = 0; m < 4; ++m)
                    #pragma unroll
                    for (int r = 0; r < 4; ++r) {
                        int row = 64 * wm + 16 * m + 4 * lq + r;
                        float v = fmaxf((acc[m][n][r] + bbc) * sc + bec, 0.0f);
                        sh[row * 128 + ((gc ^ (row & 7)) << 3) + cl] = f2b(v);
                    }
            }
            #pragma unroll
            for (int p = 0; p < 8; ++p) {
                int idx = p * 256 + tid;
                *reinterpret_cast<int4*>(&sw[idx * 8]) = wreg[p];
            }
            __syncthreads();
        }
    }

    // ---- epilogue: hfinal = att * relu(bn(acc)) via sh, then coalesced int4 stores ----
    __syncthreads();   // all MFMA reads of sh done before overwrite
    {
        const int ilg = (it * NLAY + (NLAY - 1)) * 4 + g;
        const float* bb = bhp + (size_t)ilg * 128;
        const float* gg = ghp + (size_t)ilg * 128;
        const float* be = behp + (size_t)ilg * 128;
        float attg = att[g];
        #pragma unroll
        for (int n = 0; n < 4; ++n) {
            int col = 64 * wn + 16 * n + lr;
            float sc = gg[col] * INV_STD;
            float bbc = bb[col], bec = be[col];
            int gc = col >> 3, cl = col & 7;
            #pragma unroll
            for (int m = 0; m < 4; ++m)
                #pragma unroll
                for (int r = 0; r < 4; ++r) {
                    int row = 64 * wm + 16 * m + 4 * lq + r;
                    float v = fmaxf((acc[m][n][r] + bbc) * sc + bec, 0.0f) * attg;
                    sh[row * 128 + ((gc ^ (row & 7)) << 3) + cl] = f2b(v);
                }
        }
    }
    __syncthreads();
    #pragma unroll
    for (int p = 0; p < 8; ++p) {
        int idx = p * 256 + tid;
        int row = idx >> 4, gd = idx & 15;
        int4 v = *reinterpret_cast<const int4*>(&sh[row * 128 + ((gd ^ (row & 7)) << 3)]);
        *reinterpret_cast<int4*>(&hfinal[(size_t)(r0 + row) * 128 + gd * 8]) = v;
    }
}

// ---------------- per-node CSR reduce: nf = segment_sum; fused nfb cvt + pool ----------------

__global__ void reduce_k(const unsigned short* __restrict__ hfinal,
                         const int* __restrict__ row_start, const int* __restrict__ row_ids,
                         const int* __restrict__ ntf, unsigned short* __restrict__ nfb,
                         float* __restrict__ emb, int itoff) {
    int n = blockIdx.x * 2 + (threadIdx.x >> 7);
    int c = threadIdx.x & 127;
    int s = row_start[n], e = row_start[n + 1];
    float acc = 0.0f;
    for (int r = s; r < e; ++r) {
        int rid = row_ids[r];
        acc += b2f(hfinal[(size_t)rid * 128 + c]);
    }
    nfb[(size_t)n * 128 + c] = f2b(acc);
    atomicAdd(&emb[(size_t)ntf[n] * 512 + itoff + c], acc);
}

__global__ void clamp_k(const float* __restrict__ emb, float* __restrict__ out) {
    int i = blockIdx.x * 256 + threadIdx.x;
    out[i] = fminf(emb[i], 1.0e6f);
}

// ---------------- launch ----------------

extern "C" void kernel_launch(void* const* d_in, const int* in_sizes, int n_in,
                              void* d_out, int out_size, void* d_ws, size_t ws_size,
                              hipStream_t stream) {
    (void)in_sizes; (void)n_in; (void)out_size; (void)ws_size;
    const float* pos   = (const float*)d_in[0];
    const int*   eidx  = (const int*)d_in[1];
    const int*   edxjk = (const int*)d_in[2];
    const int*   edxij = (const int*)d_in[3];
    const int*   neip  = (const int*)d_in[4];
    const int*   ntf   = (const int*)d_in[5];
    const float* Wg    = (const float*)d_in[6];
    const float* bg    = (const float*)d_in[7];
    const float* gamg  = (const float*)d_in[8];
    const float* betg  = (const float*)d_in[9];
    const float* W0    = (const float*)d_in[10];
    const float* b0    = (const float*)d_in[11];
    const float* g0    = (const float*)d_in[12];
    const float* be0   = (const float*)d_in[13];
    const float* Wh    = (const float*)d_in[14];
    const float* bhp   = (const float*)d_in[15];
    const float* ghp   = (const float*)d_in[16];
    const float* behp  = (const float*)d_in[17];
    const float* att   = (const float*)d_in[18];

    char* w = (char*)d_ws;
    size_t off = 0;
    auto alloc = [&](size_t b) -> char* {
        char* p = w + off;
        off += (b + 255) & ~(size_t)255;
        return p;
    };
    int* ints            = (int*)alloc(256);                         // counts[4],cursor[4],aoff[5]
    int* rowmap          = (int*)alloc((size_t)RMAX * 4);
    int* cnt             = (int*)alloc((size_t)N_NODES * 4);         // i-hist -> cursor
    int* row_start       = (int*)alloc((size_t)(N_NODES + 1) * 4);
    int* row_ids         = (int*)alloc((size_t)T_TRI * 4);
    unsigned short* WT0  = (unsigned short*)alloc((size_t)16 * 128 * 512 * 2);
    unsigned short* WTh  = (unsigned short*)alloc((size_t)64 * 128 * 128 * 2);
    unsigned short* geob = (unsigned short*)alloc((size_t)T_TRI * 128 * 2);
    unsigned short* nfb  = (unsigned short*)alloc((size_t)N_NODES * 128 * 2);
    unsigned short* hfin = (unsigned short*)alloc((size_t)RMAX * 128 * 2);
    float* emb           = (float*)alloc((size_t)G_POOL * 512 * 4);

    hipMemsetAsync(ints, 0, 256, stream);
    hipMemsetAsync(rowmap, 0xFF, (size_t)RMAX * 4, stream);
    hipMemsetAsync(cnt, 0, (size_t)N_NODES * 4, stream);
    hipMemsetAsync(emb, 0, (size_t)G_POOL * 512 * 4, stream);

    histboth_k<<<256, 256, 0, stream>>>(edxjk, edxij, neip, eidx, ints, cnt);
    scanoff_k<<<1, 256, 0, stream>>>(ints, cnt, row_start);
    scatboth_k<<<256, 256, 0, stream>>>(edxjk, edxij, neip, eidx, ints, rowmap, cnt, row_ids);
    t0_k<<<1024, 256, 0, stream>>>(W0, WT0);
    th_k<<<1024, 256, 0, stream>>>(Wh, WTh);
    geo_k<<<T_TRI / 16, 256, 0, stream>>>(pos, eidx, Wg, bg, gamg, betg, geob);

    for (int it = 0; it < NITER; ++it) {
        if (it == 0)
            chain_k<1><<<MT, 256, 0, stream>>>(nfb, geob, eidx, rowmap, ints + 8, WT0, b0, g0, be0,
                                               WTh, bhp, ghp, behp, att, hfin, it);
        else
            chain_k<0><<<MT, 256, 0, stream>>>(nfb, geob, eidx, rowmap, ints + 8, WT0, b0, g0, be0,
                                               WTh, bhp, ghp, behp, att, hfin, it);
        reduce_k<<<N_NODES / 2, 256, 0, stream>>>(hfin, row_start, row_ids, ntf, nfb, emb, it * 128);
    }

    clamp_k<<<1024, 256, 0, stream>>>(emb, (float*)d_out);
}

// Round 12
// 445.208 us; speedup vs baseline: 1.3633x; 1.0972x over previous
//
#include <hip/hip_runtime.h>
#include <hip/hip_bf16.h>
#include <math.h>

#define N_NODES 16384
#define T_TRI   65536
#define H_DIM   128
#define G_POOL  512
#define NITER   4
#define NLAY    4
#define RMAX    (T_TRI + 512)
#define MT64    (RMAX / 64)       // 1032 tiles of 64 rows

#define INV_STD 0.9999950000374996f

typedef __attribute__((ext_vector_type(8))) short bhalf8;
typedef __attribute__((ext_vector_type(4))) float f32x4;

__device__ __forceinline__ unsigned short f2b(float f) {
    unsigned int u = __float_as_uint(f);
    unsigned int r = (u + 0x7fffu + ((u >> 16) & 1u)) >> 16;
    return (unsigned short)r;
}
__device__ __forceinline__ float b2f(unsigned short b) {
    return __uint_as_float(((unsigned int)b) << 16);
}

// ---------------- group classification ----------------

__device__ __forceinline__ int group_of(int eij, int ejk, int nei) {
    return ((eij < nei) ? 0 : 2) + ((ejk < nei) ? 0 : 1);
}

__global__ void histboth_k(const int* __restrict__ edxjk, const int* __restrict__ edxij,
                           const int* __restrict__ neip, const int* __restrict__ eidx,
                           int* __restrict__ ints, int* __restrict__ cnt) {
    __shared__ int lc[4];
    if (threadIdx.x < 4) lc[threadIdx.x] = 0;
    __syncthreads();
    int t = blockIdx.x * 256 + threadIdx.x;
    int nei = *neip;
    int g = group_of(edxij[t], edxjk[t], nei);
    atomicAdd(&lc[g], 1);
    atomicAdd(&cnt[eidx[t]], 1);
    __syncthreads();
    if (threadIdx.x < 4) atomicAdd(&ints[threadIdx.x], lc[threadIdx.x]);
}

__global__ void scanoff_k(int* __restrict__ ints, int* __restrict__ cnt,
                          int* __restrict__ row_start) {
    __shared__ int part[256];
    int tid = threadIdx.x;
    if (tid == 0) {
        int a = 0;
        ints[8] = 0;
        for (int g = 0; g < 4; ++g) {
            a = (a + ints[g] + 127) & ~127;
            ints[9 + g] = a;
        }
    }
    int base = tid * 64;
    int s = 0;
    for (int q = 0; q < 64; ++q) s += cnt[base + q];
    part[tid] = s;
    __syncthreads();
    if (tid == 0) {
        int run = 0;
        for (int q = 0; q < 256; ++q) { int v = part[q]; part[q] = run; run += v; }
        row_start[N_NODES] = run;
    }
    __syncthreads();
    int p = part[tid];
    for (int q = 0; q < 64; ++q) {
        int c = cnt[base + q];
        row_start[base + q] = p;
        cnt[base + q] = p;
        p += c;
    }
}

__global__ void scatboth_k(const int* __restrict__ edxjk, const int* __restrict__ edxij,
                           const int* __restrict__ neip, const int* __restrict__ eidx,
                           int* __restrict__ ints, int* __restrict__ rowmap,
                           int* __restrict__ cursor, int* __restrict__ row_ids) {
    int t = blockIdx.x * 256 + threadIdx.x;
    int nei = *neip;
    int g = group_of(edxij[t], edxjk[t], nei);
    int lane = threadIdx.x & 63;
    unsigned long long msame = 0;
    #pragma unroll
    for (int q = 0; q < 4; ++q) {
        unsigned long long mq = __ballot(g == q);
        if (g == q) msame = mq;
    }
    int leader = __ffsll((long long)msame) - 1;
    int rank = __popcll(msame & ((1ull << lane) - 1ull));
    int base = 0;
    if (lane == leader) base = atomicAdd(&ints[4 + g], __popcll(msame));
    base = __shfl(base, leader);
    int pos = ints[8 + g] + base + rank;
    rowmap[pos] = t;
    int slot = atomicAdd(&cursor[eidx[t]], 1);
    row_ids[slot] = pos;
}

// ---------------- weight prep: LDS tile transpose, fp32 -> bf16 [n][k] ----------------

__global__ void t0_k(const float* __restrict__ W0, unsigned short* __restrict__ WT0) {
    __shared__ float t[32][33];
    int b = blockIdx.x;                 // 16 * 16 * 4 = 1024 tiles
    int ig = b >> 6;
    int kt = (b >> 2) & 15;
    int nt = b & 3;
    int tx = threadIdx.x & 31, ty = threadIdx.x >> 5;
    const float* src = W0 + ((size_t)ig * 512 + kt * 32) * 128 + nt * 32;
    #pragma unroll
    for (int q = 0; q < 4; ++q) { int r = q * 8 + ty; t[r][tx] = src[(size_t)r * 128 + tx]; }
    __syncthreads();
    unsigned short* dst = WT0 + ((size_t)ig * 128 + nt * 32) * 512 + kt * 32;
    #pragma unroll
    for (int q = 0; q < 4; ++q) { int r = q * 8 + ty; dst[(size_t)r * 512 + tx] = f2b(t[tx][r]); }
}

__global__ void th_k(const float* __restrict__ Wh, unsigned short* __restrict__ WTh) {
    __shared__ float t[32][33];
    int b = blockIdx.x;                 // 64 * 4 * 4 = 1024 tiles
    int ilg = b >> 4;
    int kt = (b >> 2) & 3;
    int nt = b & 3;
    int tx = threadIdx.x & 31, ty = threadIdx.x >> 5;
    const float* src = Wh + ((size_t)ilg * 128 + kt * 32) * 128 + nt * 32;
    #pragma unroll
    for (int q = 0; q < 4; ++q) { int r = q * 8 + ty; t[r][tx] = src[(size_t)r * 128 + tx]; }
    __syncthreads();
    unsigned short* dst = WTh + ((size_t)ilg * 128 + nt * 32) * 128 + kt * 32;
    #pragma unroll
    for (int q = 0; q < 4; ++q) { int r = q * 8 + ty; dst[(size_t)r * 128 + tx] = f2b(t[tx][r]); }
}

// ---------------- geo encoding (vectorized) ----------------

__global__ void geo_k(const float* __restrict__ pos, const int* __restrict__ eidx,
                      const float* __restrict__ Wg, const float* __restrict__ bg,
                      const float* __restrict__ gamg, const float* __restrict__ betg,
                      unsigned short* __restrict__ geob) {
    int t = blockIdx.x * 16 + (threadIdx.x >> 4);
    int h0 = (threadIdx.x & 15) * 8;
    int ni = eidx[t], nj = eidx[T_TRI + t], nk = eidx[2 * T_TRI + t];
    float ix = pos[2 * ni], iy = pos[2 * ni + 1];
    float jx = pos[2 * nj], jy = pos[2 * nj + 1];
    float kx = pos[2 * nk], ky = pos[2 * nk + 1];
    float v1x = jx - ix, v1y = jy - iy;
    float v2x = kx - jx, v2y = ky - jy;
    float dij = sqrtf(v1x * v1x + v1y * v1y);
    float djk = sqrtf(v2x * v2x + v2y * v2y);
    float cr = v1x * v2y - v1y * v2x;
    float dt = v1x * v2x + v1y * v2y;
    float th = atan2f(fabsf(cr), dt);
    unsigned int ov[4];
    #pragma unroll
    for (int q = 0; q < 4; ++q) {
        unsigned int lo = 0, hi = 0;
        #pragma unroll
        for (int e = 0; e < 2; ++e) {
            int h = h0 + q * 2 + e;
            float v = dij * Wg[h] + djk * Wg[128 + h] + th * Wg[256 + h] + bg[h];
            v = v * (gamg[h] * INV_STD) + betg[h];
            v = fmaxf(v, 0.0f);
            if (e == 0) lo = f2b(v); else hi = f2b(v);
        }
        ov[q] = lo | (hi << 16);
    }
    int4 o = { (int)ov[0], (int)ov[1], (int)ov[2], (int)ov[3] };
    *reinterpret_cast<int4*>(&geob[(size_t)t * 128 + h0]) = o;
}

// ---------------- fused chain, 64-row tiles, B in registers ----------------
// wave w (0..3) owns cols [32w,32w+32); acc[4][2]; LDS = 16KB h + 2x8KB A ping-pong

template<int SKIPNF>
__global__ __launch_bounds__(256, 4) void chain_k(
    const unsigned short* __restrict__ nfb, const unsigned short* __restrict__ geob,
    const int* __restrict__ eidx, const int* __restrict__ rowmap,
    const int* __restrict__ aoff, const unsigned short* __restrict__ WT0,
    const float* __restrict__ b0, const float* __restrict__ g0, const float* __restrict__ be0,
    const unsigned short* __restrict__ WTh,
    const float* __restrict__ bhp, const float* __restrict__ ghp, const float* __restrict__ behp,
    const float* __restrict__ att, unsigned short* __restrict__ hfinal,
    int it) {
    __shared__ unsigned short sh[64 * 128];      // 16 KB h tile (swizzled)
    __shared__ unsigned short sa[2][64 * 64];    // 2 x 8 KB GEMM0 A ping-pong

    const int r0 = blockIdx.x * 64;
    int g = 0;
    if (r0 >= aoff[1]) g = 1;
    if (r0 >= aoff[2]) g = 2;
    if (r0 >= aoff[3]) g = 3;
    const int tid = threadIdx.x;
    const int lane = tid & 63;
    const int w = tid >> 6;              // wave id = n-strip
    const int lr = lane & 15, lq = lane >> 4;

    // gather indices: thread stages rows p*32 + tid/8, p=0..1
    const int myrow = tid >> 3;
    const int mycolb = (tid & 7) * 8;
    int ttv[2], offi[2], offj[2], offk2[2], offt[2];
    #pragma unroll
    for (int p = 0; p < 2; ++p) {
        int row = p * 32 + myrow;
        int tt = rowmap[r0 + row];
        ttv[p] = tt;
        int ts = tt < 0 ? 0 : tt;
        offt[p] = ts * 128;
        if (!SKIPNF) {
            offi[p]  = eidx[ts] * 128;
            offj[p]  = eidx[T_TRI + ts] * 128;
            offk2[p] = eidx[2 * T_TRI + ts] * 128;
        }
    }

    f32x4 acc[4][2];
    const f32x4 zero4 = {0.f, 0.f, 0.f, 0.f};
    #pragma unroll
    for (int m = 0; m < 4; ++m)
        #pragma unroll
        for (int n = 0; n < 2; ++n) acc[m][n] = zero4;

    // ---- GEMM0: [64 gathered rows, K] x [K,128], A ping-pong, B reg-fragments ----
    const unsigned short* Wt = WT0 + (size_t)(it * 4 + g) * 128 * 512;
    constexpr int KSTEPS = SKIPNF ? 2 : 8;
    constexpr int KBASE  = SKIPNF ? 384 : 0;
    int4 ra[2];

    // prologue: stage k-step 0 into sa[0]
    {
        const int k0 = KBASE;
        const int region = k0 >> 7, half = k0 & 127;
        #pragma unroll
        for (int p = 0; p < 2; ++p) {
            int4 v = {0, 0, 0, 0};
            if (ttv[p] >= 0) {
                const unsigned short* src =
                    region == 0 ? nfb + offi[p] :
                    region == 1 ? nfb + offj[p] :
                    region == 2 ? nfb + offk2[p] :
                                  geob + offt[p];
                v = *reinterpret_cast<const int4*>(src + half + mycolb);
            }
            int row = p * 32 + myrow;
            *reinterpret_cast<int4*>(&sa[0][row * 64 + (((tid & 7) ^ (row & 7)) << 3)]) = v;
        }
        __syncthreads();
    }

    #pragma unroll
    for (int s = 0; s < KSTEPS; ++s) {
        const int cur = s & 1;
        const int k0 = KBASE + s * 64;
        if (s + 1 < KSTEPS) {    // issue next A-gather (overlaps MFMA)
            const int k1 = k0 + 64;
            const int region = k1 >> 7, half = k1 & 127;
            #pragma unroll
            for (int p = 0; p < 2; ++p) {
                int4 v = {0, 0, 0, 0};
                if (ttv[p] >= 0) {
                    const unsigned short* src =
                        region == 0 ? nfb + offi[p] :
                        region == 1 ? nfb + offj[p] :
                        region == 2 ? nfb + offk2[p] :
                                      geob + offt[p];
                    v = *reinterpret_cast<const int4*>(src + half + mycolb);
                }
                ra[p] = v;
            }
        }
        // B fragments for this step straight from L2 (natural fragment layout)
        bhalf8 rbf[2][2];
        #pragma unroll
        for (int n = 0; n < 2; ++n) {
            int nn = 32 * w + 16 * n + lr;
            #pragma unroll
            for (int ks = 0; ks < 2; ++ks)
                rbf[n][ks] = *reinterpret_cast<const bhalf8*>(Wt + (size_t)nn * 512 + k0 + ks * 32 + lq * 8);
        }
        #pragma unroll
        for (int ks = 0; ks < 2; ++ks) {
            bhalf8 af[4];
            #pragma unroll
            for (int m = 0; m < 4; ++m) {
                int row = 16 * m + lr;
                int c8 = (4 * ks + lq) ^ (row & 7);
                af[m] = *reinterpret_cast<const bhalf8*>(&sa[cur][row * 64 + (c8 << 3)]);
            }
            #pragma unroll
            for (int m = 0; m < 4; ++m)
                #pragma unroll
                for (int n = 0; n < 2; ++n)
                    acc[m][n] = __builtin_amdgcn_mfma_f32_16x16x32_bf16(af[m], rbf[n][ks], acc[m][n], 0, 0, 0);
        }
        if (s + 1 < KSTEPS) {
            #pragma unroll
            for (int p = 0; p < 2; ++p) {
                int row = p * 32 + myrow;
                *reinterpret_cast<int4*>(&sa[cur ^ 1][row * 64 + (((tid & 7) ^ (row & 7)) << 3)]) = ra[p];
            }
        }
        __syncthreads();
    }

    // h0 = relu(bn(acc)) -> sh
    {
        const float* bb = b0 + (it * 4 + g) * 128;
        const float* gg = g0 + (it * 4 + g) * 128;
        const float* be = be0 + (it * 4 + g) * 128;
        #pragma unroll
        for (int n = 0; n < 2; ++n) {
            int col = 32 * w + 16 * n + lr;
            float sc = gg[col] * INV_STD;
            float bbc = bb[col], bec = be[col];
            int gc = col >> 3, cl = col & 7;
            #pragma unroll
            for (int m = 0; m < 4; ++m)
                #pragma unroll
                for (int r = 0; r < 4; ++r) {
                    int row = 16 * m + 4 * lq + r;
                    float v = fmaxf((acc[m][n][r] + bbc) * sc + bec, 0.0f);
                    sh[row * 128 + ((gc ^ (row & 7)) << 3) + cl] = f2b(v);
                }
        }
    }
    __syncthreads();

    // ---- hidden layers: A from sh, B reg-fragments from L2 ----
    for (int l = 0; l < NLAY; ++l) {
        const unsigned short* Wl = WTh + (size_t)((it * NLAY + l) * 4 + g) * 128 * 128;
        #pragma unroll
        for (int m = 0; m < 4; ++m)
            #pragma unroll
            for (int n = 0; n < 2; ++n) acc[m][n] = zero4;
        #pragma unroll
        for (int kk = 0; kk < 4; ++kk) {
            bhalf8 af[4], bf[2];
            #pragma unroll
            for (int n = 0; n < 2; ++n) {
                int nn = 32 * w + 16 * n + lr;
                bf[n] = *reinterpret_cast<const bhalf8*>(Wl + (size_t)nn * 128 + kk * 32 + lq * 8);
            }
            #pragma unroll
            for (int m = 0; m < 4; ++m) {
                int row = 16 * m + lr;
                int gc = (4 * kk + lq) ^ (row & 7);
                af[m] = *reinterpret_cast<const bhalf8*>(&sh[row * 128 + (gc << 3)]);
            }
            #pragma unroll
            for (int m = 0; m < 4; ++m)
                #pragma unroll
                for (int n = 0; n < 2; ++n)
                    acc[m][n] = __builtin_amdgcn_mfma_f32_16x16x32_bf16(af[m], bf[n], acc[m][n], 0, 0, 0);
        }
        __syncthreads();   // all reads of sh done before overwrite
        if (l + 1 < NLAY) {
            const int ilg = (it * NLAY + l) * 4 + g;
            const float* bb = bhp + (size_t)ilg * 128;
            const float* gg = ghp + (size_t)ilg * 128;
            const float* be = behp + (size_t)ilg * 128;
            #pragma unroll
            for (int n = 0; n < 2; ++n) {
                int col = 32 * w + 16 * n + lr;
                float sc = gg[col] * INV_STD;
                float bbc = bb[col], bec = be[col];
                int gc = col >> 3, cl = col & 7;
                #pragma unroll
                for (int m = 0; m < 4; ++m)
                    #pragma unroll
                    for (int r = 0; r < 4; ++r) {
                        int row = 16 * m + 4 * lq + r;
                        float v = fmaxf((acc[m][n][r] + bbc) * sc + bec, 0.0f);
                        sh[row * 128 + ((gc ^ (row & 7)) << 3) + cl] = f2b(v);
                    }
            }
            __syncthreads();
        }
    }

    // ---- epilogue: hfinal = att * relu(bn(acc)) via sh, coalesced int4 stores ----
    {
        const int ilg = (it * NLAY + (NLAY - 1)) * 4 + g;
        const float* bb = bhp + (size_t)ilg * 128;
        const float* gg = ghp + (size_t)ilg * 128;
        const float* be = behp + (size_t)ilg * 128;
        float attg = att[g];
        #pragma unroll
        for (int n = 0; n < 2; ++n) {
            int col = 32 * w + 16 * n + lr;
            float sc = gg[col] * INV_STD;
            float bbc = bb[col], bec = be[col];
            int gc = col >> 3, cl = col & 7;
            #pragma unroll
            for (int m = 0; m < 4; ++m)
                #pragma unroll
                for (int r = 0; r < 4; ++r) {
                    int row = 16 * m + 4 * lq + r;
                    float v = fmaxf((acc[m][n][r] + bbc) * sc + bec, 0.0f) * attg;
                    sh[row * 128 + ((gc ^ (row & 7)) << 3) + cl] = f2b(v);
                }
        }
    }
    __syncthreads();
    #pragma unroll
    for (int p = 0; p < 4; ++p) {
        int idx = p * 256 + tid;
        int row = idx >> 4, gd = idx & 15;
        int4 v = *reinterpret_cast<const int4*>(&sh[row * 128 + ((gd ^ (row & 7)) << 3)]);
        *reinterpret_cast<int4*>(&hfinal[(size_t)(r0 + row) * 128 + gd * 8]) = v;
    }
}

// ---------------- per-node CSR reduce: nf = segment_sum; fused cvt + pool ----------------

__global__ void reduce_k(const unsigned short* __restrict__ hfinal,
                         const int* __restrict__ row_start, const int* __restrict__ row_ids,
                         const int* __restrict__ ntf, unsigned short* __restrict__ nfb,
                         float* __restrict__ emb, int itoff) {
    int n = blockIdx.x * 2 + (threadIdx.x >> 7);
    int c = threadIdx.x & 127;
    int s = row_start[n], e = row_start[n + 1];
    float acc = 0.0f;
    for (int r = s; r < e; ++r) {
        int rid = row_ids[r];
        acc += b2f(hfinal[(size_t)rid * 128 + c]);
    }
    nfb[(size_t)n * 128 + c] = f2b(acc);
    atomicAdd(&emb[(size_t)ntf[n] * 512 + itoff + c], acc);
}

__global__ void clamp_k(const float* __restrict__ emb, float* __restrict__ out) {
    int i = blockIdx.x * 256 + threadIdx.x;
    out[i] = fminf(emb[i], 1.0e6f);
}

// ---------------- launch ----------------

extern "C" void kernel_launch(void* const* d_in, const int* in_sizes, int n_in,
                              void* d_out, int out_size, void* d_ws, size_t ws_size,
                              hipStream_t stream) {
    (void)in_sizes; (void)n_in; (void)out_size; (void)ws_size;
    const float* pos   = (const float*)d_in[0];
    const int*   eidx  = (const int*)d_in[1];
    const int*   edxjk = (const int*)d_in[2];
    const int*   edxij = (const int*)d_in[3];
    const int*   neip  = (const int*)d_in[4];
    const int*   ntf   = (const int*)d_in[5];
    const float* Wg    = (const float*)d_in[6];
    const float* bg    = (const float*)d_in[7];
    const float* gamg  = (const float*)d_in[8];
    const float* betg  = (const float*)d_in[9];
    const float* W0    = (const float*)d_in[10];
    const float* b0    = (const float*)d_in[11];
    const float* g0    = (const float*)d_in[12];
    const float* be0   = (const float*)d_in[13];
    const float* Wh    = (const float*)d_in[14];
    const float* bhp   = (const float*)d_in[15];
    const float* ghp   = (const float*)d_in[16];
    const float* behp  = (const float*)d_in[17];
    const float* att   = (const float*)d_in[18];

    char* w = (char*)d_ws;
    size_t off = 0;
    auto alloc = [&](size_t b) -> char* {
        char* p = w + off;
        off += (b + 255) & ~(size_t)255;
        return p;
    };
    int* ints            = (int*)alloc(256);
    int* rowmap          = (int*)alloc((size_t)RMAX * 4);
    int* cnt             = (int*)alloc((size_t)N_NODES * 4);
    int* row_start       = (int*)alloc((size_t)(N_NODES + 1) * 4);
    int* row_ids         = (int*)alloc((size_t)T_TRI * 4);
    unsigned short* WT0  = (unsigned short*)alloc((size_t)16 * 128 * 512 * 2);
    unsigned short* WTh  = (unsigned short*)alloc((size_t)64 * 128 * 128 * 2);
    unsigned short* geob = (unsigned short*)alloc((size_t)T_TRI * 128 * 2);
    unsigned short* nfb  = (unsigned short*)alloc((size_t)N_NODES * 128 * 2);
    unsigned short* hfin = (unsigned short*)alloc((size_t)RMAX * 128 * 2);
    float* emb           = (float*)alloc((size_t)G_POOL * 512 * 4);

    hipMemsetAsync(ints, 0, 256, stream);
    hipMemsetAsync(rowmap, 0xFF, (size_t)RMAX * 4, stream);
    hipMemsetAsync(cnt, 0, (size_t)N_NODES * 4, stream);
    hipMemsetAsync(emb, 0, (size_t)G_POOL * 512 * 4, stream);

    histboth_k<<<256, 256, 0, stream>>>(edxjk, edxij, neip, eidx, ints, cnt);
    scanoff_k<<<1, 256, 0, stream>>>(ints, cnt, row_start);
    scatboth_k<<<256, 256, 0, stream>>>(edxjk, edxij, neip, eidx, ints, rowmap, cnt, row_ids);
    t0_k<<<1024, 256, 0, stream>>>(W0, WT0);
    th_k<<<1024, 256, 0, stream>>>(Wh, WTh);
    geo_k<<<T_TRI / 16, 256, 0, stream>>>(pos, eidx, Wg, bg, gamg, betg, geob);

    for (int it = 0; it < NITER; ++it) {
        if (it == 0)
            chain_k<1><<<MT64, 256, 0, stream>>>(nfb, geob, eidx, rowmap, ints + 8, WT0, b0, g0, be0,
                                                 WTh, bhp, ghp, behp, att, hfin, it);
        else
            chain_k<0><<<MT64, 256, 0, stream>>>(nfb, geob, eidx, rowmap, ints + 8, WT0, b0, g0, be0,
                                                 WTh, bhp, ghp, behp, att, hfin, it);
        reduce_k<<<N_NODES / 2, 256, 0, stream>>>(hfin, row_start, row_ids, ntf, nfb, emb, it * 128);
    }

    clamp_k<<<1024, 256, 0, stream>>>(emb, (float*)d_out);
}